// Round 3
// baseline (1826.388 us; speedup 1.0000x reference)
//
#include <hip/hip_runtime.h>
#include <math.h>

// Problem constants
#define B_ 2
#define S_ 2048
#define HID_ 2048
#define H_ 8
#define D_ 256
#define KV_STRIDE 512   // kv_cat: [4096][512] = K(0..255) | V(256..511)

typedef __attribute__((ext_vector_type(8))) __bf16 bf16x8;
typedef __attribute__((ext_vector_type(8))) unsigned short u16x8;
typedef __attribute__((ext_vector_type(4))) float f32x4;

__device__ __forceinline__ unsigned short bf16_rne(float x) {
    unsigned int u = __float_as_uint(x);
    return (unsigned short)((u + 0x7FFFu + ((u >> 16) & 1u)) >> 16);
}

// ---------------- fp32 -> bf16 hi/lo split (x ~= hi + lo, err ~2^-17 |x|) ----------------
__global__ __launch_bounds__(256) void split_bf16(const float* __restrict__ x,
                                                  unsigned short* __restrict__ h,
                                                  unsigned short* __restrict__ l,
                                                  int n4) {
    int i = blockIdx.x * 256 + threadIdx.x;
    if (i >= n4) return;
    float4 v = ((const float4*)x)[i];
    ushort4 hh, ll;
    hh.x = bf16_rne(v.x); ll.x = bf16_rne(v.x - __uint_as_float((unsigned int)hh.x << 16));
    hh.y = bf16_rne(v.y); ll.y = bf16_rne(v.y - __uint_as_float((unsigned int)hh.y << 16));
    hh.z = bf16_rne(v.z); ll.z = bf16_rne(v.z - __uint_as_float((unsigned int)hh.z << 16));
    hh.w = bf16_rne(v.w); ll.w = bf16_rne(v.w - __uint_as_float((unsigned int)hh.w << 16));
    ((ushort4*)h)[i] = hh;
    ((ushort4*)l)[i] = ll;
}

// ---------------- split-bf16 MFMA GEMM: C[M,N] = A[M,K] @ W[N,K]^T ----------------
// 128x128 tile, 4 waves (2x2), each wave 64x64 = 4x4 frags of 16x16, K-step 32.
// A/B frag layout (m89/m92-verified): row/col = lane&15, k = (lane>>4)*8 + e (8 contig bf16).
// C/D layout (m89-verified): col = lane&15, row = (lane>>4)*4 + reg.
// Error model: x*y ~= xh*yh + xh*yl + xl*yh (drop lo*lo, <=2^-16 rel) -> ~3e-5 overall.
__global__ __launch_bounds__(256) void gemm_mfma_split(
    const unsigned short* __restrict__ Ah, const unsigned short* __restrict__ Al,
    const unsigned short* __restrict__ Wh, const unsigned short* __restrict__ Wl,
    float* __restrict__ C, int M, int N, int K)
{
    __shared__ unsigned short As[2][128][40];  // [hi/lo][row][k], +8 pad: 80B rows, <=2-way banks
    __shared__ unsigned short Bs[2][128][40];

    const int tid  = threadIdx.x;
    const int lane = tid & 63;
    const int w    = tid >> 6;
    const int wr   = w >> 1, wc = w & 1;     // wave grid 2x2
    const int fr   = lane & 15;
    const int ko   = (lane >> 4) * 8;
    const int bm   = blockIdx.x * 128, bn = blockIdx.y * 128;

    // staging map: thread -> (row, 16-elem k-chunk)
    const int srow = tid >> 1;
    const int skc  = (tid & 1) * 16;
    const unsigned short* gAh = Ah + (size_t)(bm + srow) * K + skc;
    const unsigned short* gAl = Al + (size_t)(bm + srow) * K + skc;
    const unsigned short* gWh = Wh + (size_t)(bn + srow) * K + skc;
    const unsigned short* gWl = Wl + (size_t)(bn + srow) * K + skc;

    f32x4 acc[4][4];
#pragma unroll
    for (int i = 0; i < 4; ++i)
#pragma unroll
        for (int j = 0; j < 4; ++j)
#pragma unroll
            for (int r = 0; r < 4; ++r) acc[i][j][r] = 0.f;

    // prologue: load K-tile 0 into regs
    u16x8 ra0 = ((const u16x8*)gAh)[0], ra1 = ((const u16x8*)gAh)[1];
    u16x8 ra2 = ((const u16x8*)gAl)[0], ra3 = ((const u16x8*)gAl)[1];
    u16x8 rb0 = ((const u16x8*)gWh)[0], rb1 = ((const u16x8*)gWh)[1];
    u16x8 rb2 = ((const u16x8*)gWl)[0], rb3 = ((const u16x8*)gWl)[1];

    for (int k0 = 0; k0 < K; k0 += 32) {
        *(u16x8*)&As[0][srow][skc]     = ra0;
        *(u16x8*)&As[0][srow][skc + 8] = ra1;
        *(u16x8*)&As[1][srow][skc]     = ra2;
        *(u16x8*)&As[1][srow][skc + 8] = ra3;
        *(u16x8*)&Bs[0][srow][skc]     = rb0;
        *(u16x8*)&Bs[0][srow][skc + 8] = rb1;
        *(u16x8*)&Bs[1][srow][skc]     = rb2;
        *(u16x8*)&Bs[1][srow][skc + 8] = rb3;
        __syncthreads();

        if (k0 + 32 < K) {  // prefetch next K-tile; latency hides under MFMAs below
            const unsigned short* nAh = gAh + k0 + 32;
            const unsigned short* nAl = gAl + k0 + 32;
            const unsigned short* nWh = gWh + k0 + 32;
            const unsigned short* nWl = gWl + k0 + 32;
            ra0 = ((const u16x8*)nAh)[0]; ra1 = ((const u16x8*)nAh)[1];
            ra2 = ((const u16x8*)nAl)[0]; ra3 = ((const u16x8*)nAl)[1];
            rb0 = ((const u16x8*)nWh)[0]; rb1 = ((const u16x8*)nWh)[1];
            rb2 = ((const u16x8*)nWl)[0]; rb3 = ((const u16x8*)nWl)[1];
        }

        bf16x8 ah[4], al4[4], bh[4], bl[4];
#pragma unroll
        for (int i = 0; i < 4; ++i) {
            ah[i]  = *(const bf16x8*)&As[0][wr * 64 + i * 16 + fr][ko];
            al4[i] = *(const bf16x8*)&As[1][wr * 64 + i * 16 + fr][ko];
            bh[i]  = *(const bf16x8*)&Bs[0][wc * 64 + i * 16 + fr][ko];
            bl[i]  = *(const bf16x8*)&Bs[1][wc * 64 + i * 16 + fr][ko];
        }
#pragma unroll
        for (int i = 0; i < 4; ++i)
#pragma unroll
            for (int j = 0; j < 4; ++j) {
                acc[i][j] = __builtin_amdgcn_mfma_f32_16x16x32_bf16(ah[i],  bh[j], acc[i][j], 0, 0, 0);
                acc[i][j] = __builtin_amdgcn_mfma_f32_16x16x32_bf16(ah[i],  bl[j], acc[i][j], 0, 0, 0);
                acc[i][j] = __builtin_amdgcn_mfma_f32_16x16x32_bf16(al4[i], bh[j], acc[i][j], 0, 0, 0);
            }
        __syncthreads();
    }

#pragma unroll
    for (int i = 0; i < 4; ++i) {
        int r0 = bm + wr * 64 + i * 16 + (lane >> 4) * 4;
#pragma unroll
        for (int j = 0; j < 4; ++j) {
            int c = bn + wc * 64 + j * 16 + fr;
#pragma unroll
            for (int r = 0; r < 4; ++r)
                C[(size_t)(r0 + r) * N + c] = acc[i][j][r];
        }
    }
}

// ---------------- RoPE: rotate q in place; rotate k (from kv_cat) -> transposed kT[B,D,S] ----------------
__global__ __launch_bounds__(128) void rope_kernel(float* __restrict__ q,
                                                   const float* __restrict__ kv,
                                                   float* __restrict__ kT,
                                                   const int* __restrict__ pos) {
    int bs = blockIdx.x;            // b*S + s
    int b = bs >> 11;
    int s = bs & 2047;
    int d = threadIdx.x;            // 0..127 (pair index)
    float p = (float)pos[bs];
    float inv = expf(-(2.0f * (float)d / (float)D_) * 9.210340371976184f);  // log(10000)
    float sn, cs;
    sincosf(p * inv, &sn, &cs);

    float* qp = q + (size_t)bs * (H_ * D_);
#pragma unroll
    for (int h = 0; h < H_; ++h) {
        float x1 = qp[h * D_ + d];
        float x2 = qp[h * D_ + d + 128];
        qp[h * D_ + d]       = x1 * cs - x2 * sn;
        qp[h * D_ + d + 128] = x2 * cs + x1 * sn;
    }
    const float* kp = kv + (size_t)bs * KV_STRIDE;
    float x1 = kp[d], x2 = kp[d + 128];
    kT[((size_t)b * D_ + d) * S_ + s]       = x1 * cs - x2 * sn;
    kT[((size_t)b * D_ + d + 128) * S_ + s] = x2 * cs + x1 * sn;
}

// ---------------- Flash attention (fp32). KV=1: K/V shared across heads. ----------------
// Block = 256 threads = 4 waves, one (b,h) x 16 q-rows per block. After the Q-load
// barrier every wave touches ONLY its own 4 rows of p_s and reads q_s read-only,
// so the main loop has NO barriers -> waves drift phase and overlap QK^T with PV.
__global__ __launch_bounds__(256) void attn_kernel(const float* __restrict__ q,
                                                   const float* __restrict__ kT,
                                                   const float* __restrict__ kv,
                                                   const float* __restrict__ mask,
                                                   float* __restrict__ out) {
    const int QT = 16, KT = 256;
    const int nqt = S_ / QT;  // 128
    int blk = blockIdx.x;
    int b = blk / (H_ * nqt);
    int rem = blk % (H_ * nqt);
    int h = rem / nqt;
    int i0 = (rem % nqt) * QT;

    __shared__ __align__(16) float q_s[QT][D_];
    __shared__ __align__(16) float p_s[QT][KT];

    int tid = threadIdx.x;
    int lane = tid & 63;
    int rg = tid >> 6;
    const int row0 = rg * 4;

    for (int t = tid; t < QT * D_ / 4; t += 256) {
        int r = t >> 6;
        int c = (t & 63) << 2;
        *(float4*)&q_s[r][c] =
            *(const float4*)&q[(size_t)(b * S_ + i0 + r) * (H_ * D_) + h * D_ + c];
    }
    __syncthreads();

    float m_run[4], l_run[4];
    float o_acc[4][4] = {{0.f}};
#pragma unroll
    for (int r = 0; r < 4; ++r) { m_run[r] = -INFINITY; l_run[r] = 0.f; }

    const float scale = 0.0625f;  // 1/sqrt(256)

    for (int j0 = 0; j0 < S_; j0 += KT) {
        float sc[4][4] = {{0.f}};
        const float* kp = &kT[(size_t)b * D_ * S_ + j0 + lane * 4];
#pragma unroll 2
        for (int d4 = 0; d4 < D_; d4 += 4) {
            float qv[4][4];
#pragma unroll
            for (int r = 0; r < 4; ++r)
                *(float4*)&qv[r][0] = *(const float4*)&q_s[row0 + r][d4];
#pragma unroll
            for (int dd = 0; dd < 4; ++dd) {
                float4 kvv = *(const float4*)&kp[(size_t)(d4 + dd) * S_];
#pragma unroll
                for (int r = 0; r < 4; ++r) {
                    sc[r][0] += qv[r][dd] * kvv.x;
                    sc[r][1] += qv[r][dd] * kvv.y;
                    sc[r][2] += qv[r][dd] * kvv.z;
                    sc[r][3] += qv[r][dd] * kvv.w;
                }
            }
        }
        float rmax[4];
#pragma unroll
        for (int r = 0; r < 4; ++r) {
            float4 mk = *(const float4*)&mask[(size_t)(b * S_ + i0 + row0 + r) * S_ + j0 + lane * 4];
            sc[r][0] = sc[r][0] * scale + mk.x;
            sc[r][1] = sc[r][1] * scale + mk.y;
            sc[r][2] = sc[r][2] * scale + mk.z;
            sc[r][3] = sc[r][3] * scale + mk.w;
            rmax[r] = fmaxf(fmaxf(sc[r][0], sc[r][1]), fmaxf(sc[r][2], sc[r][3]));
        }
#pragma unroll
        for (int off = 1; off < 64; off <<= 1)
#pragma unroll
            for (int r = 0; r < 4; ++r) rmax[r] = fmaxf(rmax[r], __shfl_xor(rmax[r], off));

        float corr[4], psum[4];
#pragma unroll
        for (int r = 0; r < 4; ++r) {
            float m_new = fmaxf(m_run[r], rmax[r]);
            corr[r] = expf(m_run[r] - m_new);
            m_run[r] = m_new;
            float p0 = expf(sc[r][0] - m_new);
            float p1 = expf(sc[r][1] - m_new);
            float p2 = expf(sc[r][2] - m_new);
            float p3 = expf(sc[r][3] - m_new);
            psum[r] = (p0 + p1) + (p2 + p3);
            float4 pv4 = {p0, p1, p2, p3};
            *(float4*)&p_s[row0 + r][lane * 4] = pv4;  // own rows only
        }
#pragma unroll
        for (int off = 1; off < 64; off <<= 1)
#pragma unroll
            for (int r = 0; r < 4; ++r) psum[r] += __shfl_xor(psum[r], off);
#pragma unroll
        for (int r = 0; r < 4; ++r) l_run[r] = l_run[r] * corr[r] + psum[r];

#pragma unroll
        for (int r = 0; r < 4; ++r)
#pragma unroll
            for (int c = 0; c < 4; ++c) o_acc[r][c] *= corr[r];

        const float* vp = &kv[(size_t)(b * S_ + j0) * KV_STRIDE + 256 + lane * 4];
#pragma unroll 2
        for (int j4 = 0; j4 < KT; j4 += 4) {
            float pv[4][4];
#pragma unroll
            for (int r = 0; r < 4; ++r)
                *(float4*)&pv[r][0] = *(const float4*)&p_s[row0 + r][j4];  // own rows only
#pragma unroll
            for (int jj = 0; jj < 4; ++jj) {
                float4 vv = *(const float4*)&vp[(size_t)(j4 + jj) * KV_STRIDE];
#pragma unroll
                for (int r = 0; r < 4; ++r) {
                    o_acc[r][0] += pv[r][jj] * vv.x;
                    o_acc[r][1] += pv[r][jj] * vv.y;
                    o_acc[r][2] += pv[r][jj] * vv.z;
                    o_acc[r][3] += pv[r][jj] * vv.w;
                }
            }
        }
        // no barrier: waves are independent here (own-row p_s discipline)
    }

#pragma unroll
    for (int r = 0; r < 4; ++r) {
        float inv_l = 1.0f / l_run[r];
        float4 o = {o_acc[r][0] * inv_l, o_acc[r][1] * inv_l,
                    o_acc[r][2] * inv_l, o_acc[r][3] * inv_l};
        *(float4*)&out[(size_t)(b * S_ + i0 + row0 + r) * (H_ * D_) + h * D_ + lane * 4] = o;
    }
}

// ---------------- launcher ----------------
// ws layout (byte offsets), total 117,440,512 B = 112 MB:
//   q      [0,          33554432)  fp32 [4096][2048]; later reused as ao_h/ao_l (bf16 planes)
//   kv_cat [33554432,   41943040)  fp32 [4096][512]  (K | V)
//   kT     [41943040,   46137344)  fp32 [2][256][2048]
//   R1     [46137344,   79691776)  hs_h | hs_l (bf16); later reused as ao fp32
//   wq_h/l [79691776,   96468992)
//   wkv_h/l[96468992,  100663296)  (wk rows 0..255, wv rows 256..511)
//   wo_h/l [100663296, 117440512)
extern "C" void kernel_launch(void* const* d_in, const int* in_sizes, int n_in,
                              void* d_out, int out_size, void* d_ws, size_t ws_size,
                              hipStream_t stream) {
    const float* hs   = (const float*)d_in[0];
    const float* mask = (const float*)d_in[1];
    const int*   pos  = (const int*)d_in[2];
    const float* wq   = (const float*)d_in[3];
    const float* wk   = (const float*)d_in[4];
    const float* wv   = (const float*)d_in[5];
    const float* wo   = (const float*)d_in[6];
    float* out = (float*)d_out;

    char* ws = (char*)d_ws;
    float*          q     = (float*)(ws + 0);
    float*          kvb   = (float*)(ws + 33554432);
    float*          kT    = (float*)(ws + 41943040);
    unsigned short* hs_h  = (unsigned short*)(ws + 46137344);
    unsigned short* hs_l  = (unsigned short*)(ws + 62914560);
    float*          ao    = (float*)(ws + 46137344);   // overlays hs_h/hs_l (dead by then)
    unsigned short* wq_h  = (unsigned short*)(ws + 79691776);
    unsigned short* wq_l  = (unsigned short*)(ws + 88080384);
    unsigned short* wkv_h = (unsigned short*)(ws + 96468992);
    unsigned short* wkv_l = (unsigned short*)(ws + 98566144);
    unsigned short* wo_h  = (unsigned short*)(ws + 100663296);
    unsigned short* wo_l  = (unsigned short*)(ws + 109051904);
    unsigned short* ao_h  = (unsigned short*)(ws + 0);         // overlays q (dead by then)
    unsigned short* ao_l  = (unsigned short*)(ws + 16777216);

    const int M = B_ * S_;  // 4096

    // 1) split inputs to bf16 hi/lo planes
    split_bf16<<<dim3(2097152 / 256), dim3(256), 0, stream>>>(hs, hs_h, hs_l, 2097152);
    split_bf16<<<dim3(1048576 / 256), dim3(256), 0, stream>>>(wq, wq_h, wq_l, 1048576);
    split_bf16<<<dim3(131072 / 256),  dim3(256), 0, stream>>>(wk, wkv_h, wkv_l, 131072);
    split_bf16<<<dim3(131072 / 256),  dim3(256), 0, stream>>>(wv, wkv_h + 524288, wkv_l + 524288, 131072);
    split_bf16<<<dim3(1048576 / 256), dim3(256), 0, stream>>>(wo, wo_h, wo_l, 1048576);

    // 2) projections (split-bf16 MFMA)
    gemm_mfma_split<<<dim3(M / 128, 16), dim3(256), 0, stream>>>(hs_h, hs_l, wq_h, wq_l, q,   M, H_ * D_, HID_);
    gemm_mfma_split<<<dim3(M / 128, 4),  dim3(256), 0, stream>>>(hs_h, hs_l, wkv_h, wkv_l, kvb, M, KV_STRIDE, HID_);

    // 3) RoPE (q in place, k -> transposed kT)
    rope_kernel<<<dim3(B_ * S_), dim3(128), 0, stream>>>(q, kvb, kT, pos);

    // 4) attention
    attn_kernel<<<dim3(B_ * H_ * (S_ / 16)), dim3(256), 0, stream>>>(q, kT, kvb, mask, ao);

    // 5) output projection
    split_bf16<<<dim3(2097152 / 256), dim3(256), 0, stream>>>(ao, ao_h, ao_l, 2097152);
    gemm_mfma_split<<<dim3(M / 128, 16), dim3(256), 0, stream>>>(ao_h, ao_l, wo_h, wo_l, out, M, HID_, HID_);
}

// Round 5
// 823.801 us; speedup vs baseline: 2.2170x; 2.2170x over previous
//
#include <hip/hip_runtime.h>
#include <math.h>

// Problem constants
#define B_ 2
#define S_ 2048
#define HID_ 2048
#define H_ 8
#define D_ 256
#define KV_STRIDE 512   // kv_cat: [4096][512] = K(0..255) | V(256..511)

typedef __attribute__((ext_vector_type(8))) __bf16 bf16x8;
typedef __attribute__((ext_vector_type(8))) unsigned short u16x8;
typedef __attribute__((ext_vector_type(4))) float f32x4;

__device__ __forceinline__ unsigned short bf16_rne(float x) {
    unsigned int u = __float_as_uint(x);
    return (unsigned short)((u + 0x7FFFu + ((u >> 16) & 1u)) >> 16);
}

// ---------------- fp32 -> bf16 hi/lo split (x ~= hi + lo, err ~2^-17 |x|) ----------------
__global__ __launch_bounds__(256) void split_bf16(const float* __restrict__ x,
                                                  unsigned short* __restrict__ h,
                                                  unsigned short* __restrict__ l,
                                                  int n4) {
    int i = blockIdx.x * 256 + threadIdx.x;
    if (i >= n4) return;
    float4 v = ((const float4*)x)[i];
    ushort4 hh, ll;
    hh.x = bf16_rne(v.x); ll.x = bf16_rne(v.x - __uint_as_float((unsigned int)hh.x << 16));
    hh.y = bf16_rne(v.y); ll.y = bf16_rne(v.y - __uint_as_float((unsigned int)hh.y << 16));
    hh.z = bf16_rne(v.z); ll.z = bf16_rne(v.z - __uint_as_float((unsigned int)hh.z << 16));
    hh.w = bf16_rne(v.w); ll.w = bf16_rne(v.w - __uint_as_float((unsigned int)hh.w << 16));
    ((ushort4*)h)[i] = hh;
    ((ushort4*)l)[i] = ll;
}

// ---------------- split-bf16 MFMA GEMM: C[M,N] = A[M,K] @ W[N,K]^T (VALIDATED R3) --------
__global__ __launch_bounds__(256) void gemm_mfma_split(
    const unsigned short* __restrict__ Ah, const unsigned short* __restrict__ Al,
    const unsigned short* __restrict__ Wh, const unsigned short* __restrict__ Wl,
    float* __restrict__ C, int M, int N, int K)
{
    __shared__ unsigned short As[2][128][40];
    __shared__ unsigned short Bs[2][128][40];

    const int tid  = threadIdx.x;
    const int lane = tid & 63;
    const int w    = tid >> 6;
    const int wr   = w >> 1, wc = w & 1;
    const int fr   = lane & 15;
    const int ko   = (lane >> 4) * 8;
    const int bm   = blockIdx.x * 128, bn = blockIdx.y * 128;

    const int srow = tid >> 1;
    const int skc  = (tid & 1) * 16;
    const unsigned short* gAh = Ah + (size_t)(bm + srow) * K + skc;
    const unsigned short* gAl = Al + (size_t)(bm + srow) * K + skc;
    const unsigned short* gWh = Wh + (size_t)(bn + srow) * K + skc;
    const unsigned short* gWl = Wl + (size_t)(bn + srow) * K + skc;

    f32x4 acc[4][4];
#pragma unroll
    for (int i = 0; i < 4; ++i)
#pragma unroll
        for (int j = 0; j < 4; ++j)
#pragma unroll
            for (int r = 0; r < 4; ++r) acc[i][j][r] = 0.f;

    u16x8 ra0 = ((const u16x8*)gAh)[0], ra1 = ((const u16x8*)gAh)[1];
    u16x8 ra2 = ((const u16x8*)gAl)[0], ra3 = ((const u16x8*)gAl)[1];
    u16x8 rb0 = ((const u16x8*)gWh)[0], rb1 = ((const u16x8*)gWh)[1];
    u16x8 rb2 = ((const u16x8*)gWl)[0], rb3 = ((const u16x8*)gWl)[1];

    for (int k0 = 0; k0 < K; k0 += 32) {
        *(u16x8*)&As[0][srow][skc]     = ra0;
        *(u16x8*)&As[0][srow][skc + 8] = ra1;
        *(u16x8*)&As[1][srow][skc]     = ra2;
        *(u16x8*)&As[1][srow][skc + 8] = ra3;
        *(u16x8*)&Bs[0][srow][skc]     = rb0;
        *(u16x8*)&Bs[0][srow][skc + 8] = rb1;
        *(u16x8*)&Bs[1][srow][skc]     = rb2;
        *(u16x8*)&Bs[1][srow][skc + 8] = rb3;
        __syncthreads();

        if (k0 + 32 < K) {
            const unsigned short* nAh = gAh + k0 + 32;
            const unsigned short* nAl = gAl + k0 + 32;
            const unsigned short* nWh = gWh + k0 + 32;
            const unsigned short* nWl = gWl + k0 + 32;
            ra0 = ((const u16x8*)nAh)[0]; ra1 = ((const u16x8*)nAh)[1];
            ra2 = ((const u16x8*)nAl)[0]; ra3 = ((const u16x8*)nAl)[1];
            rb0 = ((const u16x8*)nWh)[0]; rb1 = ((const u16x8*)nWh)[1];
            rb2 = ((const u16x8*)nWl)[0]; rb3 = ((const u16x8*)nWl)[1];
        }

        bf16x8 ah[4], al4[4], bh[4], bl[4];
#pragma unroll
        for (int i = 0; i < 4; ++i) {
            ah[i]  = *(const bf16x8*)&As[0][wr * 64 + i * 16 + fr][ko];
            al4[i] = *(const bf16x8*)&As[1][wr * 64 + i * 16 + fr][ko];
            bh[i]  = *(const bf16x8*)&Bs[0][wc * 64 + i * 16 + fr][ko];
            bl[i]  = *(const bf16x8*)&Bs[1][wc * 64 + i * 16 + fr][ko];
        }
#pragma unroll
        for (int i = 0; i < 4; ++i)
#pragma unroll
            for (int j = 0; j < 4; ++j) {
                acc[i][j] = __builtin_amdgcn_mfma_f32_16x16x32_bf16(ah[i],  bh[j], acc[i][j], 0, 0, 0);
                acc[i][j] = __builtin_amdgcn_mfma_f32_16x16x32_bf16(ah[i],  bl[j], acc[i][j], 0, 0, 0);
                acc[i][j] = __builtin_amdgcn_mfma_f32_16x16x32_bf16(al4[i], bh[j], acc[i][j], 0, 0, 0);
            }
        __syncthreads();
    }

#pragma unroll
    for (int i = 0; i < 4; ++i) {
        int r0 = bm + wr * 64 + i * 16 + (lane >> 4) * 4;
#pragma unroll
        for (int j = 0; j < 4; ++j) {
            int c = bn + wc * 64 + j * 16 + fr;
#pragma unroll
            for (int r = 0; r < 4; ++r)
                C[(size_t)(r0 + r) * N + c] = acc[i][j][r];
        }
    }
}

// ---------------- RoPE: q in place (fp32); K -> rope'd bf16 hi/lo planes [B][S][256] -----
__global__ __launch_bounds__(128) void rope_kernel(float* __restrict__ q,
                                                   const float* __restrict__ kv,
                                                   unsigned short* __restrict__ k_h,
                                                   unsigned short* __restrict__ k_l,
                                                   const int* __restrict__ pos) {
    int bs = blockIdx.x;
    int d = threadIdx.x;            // 0..127 (pair index)
    float p = (float)pos[bs];
    float inv = expf(-(2.0f * (float)d / (float)D_) * 9.210340371976184f);  // log(10000)
    float sn, cs;
    sincosf(p * inv, &sn, &cs);

    float* qp = q + (size_t)bs * (H_ * D_);
#pragma unroll
    for (int h = 0; h < H_; ++h) {
        float x1 = qp[h * D_ + d];
        float x2 = qp[h * D_ + d + 128];
        qp[h * D_ + d]       = x1 * cs - x2 * sn;
        qp[h * D_ + d + 128] = x2 * cs + x1 * sn;
    }
    const float* kp = kv + (size_t)bs * KV_STRIDE;
    float x1 = kp[d], x2 = kp[d + 128];
    float y1 = x1 * cs - x2 * sn;
    float y2 = x2 * cs + x1 * sn;
    unsigned short h1 = bf16_rne(y1);
    unsigned short h2 = bf16_rne(y2);
    size_t o = (size_t)bs * D_ + d;
    k_h[o]       = h1;
    k_l[o]       = bf16_rne(y1 - __uint_as_float((unsigned int)h1 << 16));
    k_h[o + 128] = h2;
    k_l[o + 128] = bf16_rne(y2 - __uint_as_float((unsigned int)h2 << 16));
}

// ---------------- V: transpose + split -> vT_h/vT_l [B][256][S] bf16 ----------------
__global__ __launch_bounds__(256) void vsplitT(const float* __restrict__ kvb,
                                               unsigned short* __restrict__ vTh,
                                               unsigned short* __restrict__ vTl) {
    __shared__ float ts[64][65];
    const int blk = blockIdx.x;       // b*128 + dt*32 + jt
    const int b  = blk >> 7;
    const int dt = (blk >> 5) & 3;
    const int jt = blk & 31;
    const int tid = threadIdx.x;
    const int jj = tid >> 2;            // 0..63
    const int dc = (tid & 3) * 16;
    const float* src = kvb + (size_t)(b * S_ + jt * 64 + jj) * KV_STRIDE + 256 + dt * 64 + dc;
#pragma unroll
    for (int i = 0; i < 16; i += 4) {
        float4 v4 = *(const float4*)(src + i);
        ts[jj][dc + i + 0] = v4.x;
        ts[jj][dc + i + 1] = v4.y;
        ts[jj][dc + i + 2] = v4.z;
        ts[jj][dc + i + 3] = v4.w;
    }
    __syncthreads();
    const int dd = tid >> 2;            // 0..63
    const int jc = (tid & 3) * 16;
    size_t o = (size_t)(b * 256 + dt * 64 + dd) * S_ + jt * 64 + jc;
#pragma unroll
    for (int i = 0; i < 16; i += 8) {
        u16x8 hh, ll;
#pragma unroll
        for (int e = 0; e < 8; ++e) {
            float f = ts[jc + i + e][dd];
            unsigned short hb = bf16_rne(f);
            hh[e] = hb;
            ll[e] = bf16_rne(f - __uint_as_float((unsigned int)hb << 16));
        }
        *(u16x8*)(vTh + o + i) = hh;
        *(u16x8*)(vTl + o + i) = ll;
    }
}

// ---------------- MFMA flash attention ----------------
// Block = 512 thr = 8 waves; per block: one (b,h) x 128 q-rows. Wave w owns rows w*16..+15.
// j-tile = 16 keys. P (hi/lo split) is zero-padded k=16->32 so the validated 16x16x32 MFMA
// does PV. NaN-safety (R4 post-mortem): ALL k>=16 B-operand (V) reads must be finite ->
// Vs fully zero-initialized (incl. pad cols 16..23) + one absorber row for the kg=3
// 8-element overrun into the next row. 0 x 0/finite = 0; never 0 x uninit(NaN).
// Frag layouts (HW-validated R3): A/B: row|col=lane&15, k=(lane>>4)*8+e; C: col=lane&15, row=(lane>>4)*4+r.
__global__ __launch_bounds__(512) void attn_mfma(
    const float* __restrict__ q,
    const unsigned short* __restrict__ k_h,
    const unsigned short* __restrict__ k_l,
    const unsigned short* __restrict__ vTh,
    const unsigned short* __restrict__ vTl,
    const float* __restrict__ mask,
    float* __restrict__ out)
{
    __shared__ __align__(16) unsigned short Ks[2][16][264];    // 16896 B
    __shared__ __align__(16) unsigned short Vs[2][257][24];    // 24672 B (row 256 = absorber)
    __shared__ __align__(16) unsigned short Ps[2][8][16][40];  // 20480 B (hi/lo; cols 16..31 zeroed)
    // total 62048 B < 64 KB

    const int tid  = threadIdx.x;
    const int lane = tid & 63;
    const int w    = tid >> 6;          // 0..7
    const int fr   = lane & 15;
    const int kg   = lane >> 4;         // 0..3
    const int nqt  = S_ / 128;          // 16
    const int b    = blockIdx.x / (H_ * nqt);
    const int rem  = blockIdx.x % (H_ * nqt);
    const int h    = rem / nqt;
    const int i0   = (rem % nqt) * 128;

    // ---- one-time LDS sanitization (ordered before use by first loop barrier) ----
    {
        u16x8 z = {0, 0, 0, 0, 0, 0, 0, 0};
        // zero ALL of Vs: 2*257*24 = 12336 u16 = 1542 x u16x8
        unsigned short* vz = &Vs[0][0][0];
        for (int i = tid * 8; i < 12336; i += 512 * 8)
            *(u16x8*)(vz + i) = z;
        // zero P pad cols 16..31 for both planes: 2*8*16 rows x 16 cols = 512 x u16x8
        int pp = tid >> 8, pw = (tid >> 5) & 7, pr = (tid >> 1) & 15, ph8 = (tid & 1) * 8;
        *(u16x8*)&Ps[pp][pw][pr][16 + ph8] = z;
    }

    // ---- Q fragments (hi/lo), rows w*16+fr, 8 d-ksteps ----
    bf16x8 qh[8], ql[8];
    {
        const int qrow = i0 + w * 16 + fr;
        const float* qp = q + (size_t)(b * S_ + qrow) * (H_ * D_) + h * D_ + kg * 8;
#pragma unroll
        for (int ks = 0; ks < 8; ++ks) {
            float4 f0 = *(const float4*)(qp + ks * 32);
            float4 f1 = *(const float4*)(qp + ks * 32 + 4);
            float f[8] = {f0.x, f0.y, f0.z, f0.w, f1.x, f1.y, f1.z, f1.w};
            u16x8 hh, ll;
#pragma unroll
            for (int e = 0; e < 8; ++e) {
                unsigned short hb = bf16_rne(f[e]);
                hh[e] = hb;
                ll[e] = bf16_rne(f[e] - __uint_as_float((unsigned int)hb << 16));
            }
            qh[ks] = *(bf16x8*)&hh;
            ql[ks] = *(bf16x8*)&ll;
        }
    }

    f32x4 acc[16];
#pragma unroll
    for (int cf = 0; cf < 16; ++cf) acc[cf] = f32x4{0.f, 0.f, 0.f, 0.f};
    float m_run[4], l_run[4];
#pragma unroll
    for (int r = 0; r < 4; ++r) { m_run[r] = -1e30f; l_run[r] = 0.f; }

    // staging maps (512 threads)
    const int skp = tid >> 8;              // K/V plane
    const int skr = (tid >> 4) & 15;       // K row (j-local)
    const int skc = (tid & 15) * 16;       // K col (u16)
    const int svd = tid & 255;             // V d-row
    const unsigned short* gK = (skp ? k_l : k_h) + (size_t)(b * S_ + skr) * 256 + skc;
    const unsigned short* gV = (skp ? vTl : vTh) + (size_t)(b * 256 + svd) * S_;

    u16x8 rk0 = *(const u16x8*)(gK);
    u16x8 rk1 = *(const u16x8*)(gK + 8);
    u16x8 rv0 = *(const u16x8*)(gV);
    u16x8 rv1 = *(const u16x8*)(gV + 8);

    const float scale = 0.0625f;  // 1/sqrt(256)

    for (int j0 = 0; j0 < S_; j0 += 16) {
        __syncthreads();   // previous tile's compute done; LDS writable (also orders init)
        *(u16x8*)&Ks[skp][skr][skc]     = rk0;
        *(u16x8*)&Ks[skp][skr][skc + 8] = rk1;
        *(u16x8*)&Vs[skp][svd][0]       = rv0;
        *(u16x8*)&Vs[skp][svd][8]       = rv1;
        if (j0 + 16 < S_) {  // prefetch next tile (latency hides under compute below)
            rk0 = *(const u16x8*)(gK + (size_t)(j0 + 16) * 256);
            rk1 = *(const u16x8*)(gK + (size_t)(j0 + 16) * 256 + 8);
            rv0 = *(const u16x8*)(gV + j0 + 16);
            rv1 = *(const u16x8*)(gV + j0 + 24);
        }
        __syncthreads();   // tile staged

        // ---- QK^T (3-term split) ----
        f32x4 sc = {0.f, 0.f, 0.f, 0.f};
#pragma unroll
        for (int ks = 0; ks < 8; ++ks) {
            bf16x8 bh = *(const bf16x8*)&Ks[0][fr][ks * 32 + kg * 8];
            bf16x8 bl = *(const bf16x8*)&Ks[1][fr][ks * 32 + kg * 8];
            sc = __builtin_amdgcn_mfma_f32_16x16x32_bf16(qh[ks], bh, sc, 0, 0, 0);
            sc = __builtin_amdgcn_mfma_f32_16x16x32_bf16(qh[ks], bl, sc, 0, 0, 0);
            sc = __builtin_amdgcn_mfma_f32_16x16x32_bf16(ql[ks], bh, sc, 0, 0, 0);
        }

        // ---- scale + mask; C-frag element r: row=kg*4+r, col=fr ----
        float sv[4];
#pragma unroll
        for (int r = 0; r < 4; ++r)
            sv[r] = sc[r] * scale
                  + mask[(size_t)(b * S_ + i0 + w * 16 + kg * 4 + r) * S_ + j0 + fr];

        // ---- row max over the 16 cols (shfl within 16-lane group) ----
        float rmax[4];
#pragma unroll
        for (int r = 0; r < 4; ++r) rmax[r] = sv[r];
#pragma unroll
        for (int off = 1; off < 16; off <<= 1)
#pragma unroll
            for (int r = 0; r < 4; ++r)
                rmax[r] = fmaxf(rmax[r], __shfl_xor(rmax[r], off));

        // ---- online softmax update (P split hi/lo before bf16 store) ----
        float corr[4], psum[4];
#pragma unroll
        for (int r = 0; r < 4; ++r) {
            float mn = fmaxf(m_run[r], rmax[r]);
            corr[r] = __expf(m_run[r] - mn);
            m_run[r] = mn;
            float p = __expf(sv[r] - mn);
            psum[r] = p;
            unsigned short phh = bf16_rne(p);
            Ps[0][w][kg * 4 + r][fr] = phh;                                            // own wave only
            Ps[1][w][kg * 4 + r][fr] = bf16_rne(p - __uint_as_float((unsigned int)phh << 16));
        }
#pragma unroll
        for (int off = 1; off < 16; off <<= 1)
#pragma unroll
            for (int r = 0; r < 4; ++r) psum[r] += __shfl_xor(psum[r], off);
#pragma unroll
        for (int r = 0; r < 4; ++r) l_run[r] = l_run[r] * corr[r] + psum[r];

        // ---- rescale O ----
#pragma unroll
        for (int cf = 0; cf < 16; ++cf)
#pragma unroll
            for (int r = 0; r < 4; ++r) acc[cf][r] *= corr[r];

        // ---- PV, 3-term split (P zero-padded to k=32; all k>=16 V reads finite) ----
        bf16x8 pah = *(const bf16x8*)&Ps[0][w][fr][kg * 8];
        bf16x8 pal = *(const bf16x8*)&Ps[1][w][fr][kg * 8];
#pragma unroll
        for (int cf = 0; cf < 16; ++cf) {
            bf16x8 vh = *(const bf16x8*)&Vs[0][cf * 16 + fr][kg * 8];
            bf16x8 vl = *(const bf16x8*)&Vs[1][cf * 16 + fr][kg * 8];
            acc[cf] = __builtin_amdgcn_mfma_f32_16x16x32_bf16(pah, vh, acc[cf], 0, 0, 0);
            acc[cf] = __builtin_amdgcn_mfma_f32_16x16x32_bf16(pah, vl, acc[cf], 0, 0, 0);
            acc[cf] = __builtin_amdgcn_mfma_f32_16x16x32_bf16(pal, vh, acc[cf], 0, 0, 0);
        }
    }

    // ---- epilogue ----
#pragma unroll
    for (int r = 0; r < 4; ++r) {
        float invl = 1.0f / l_run[r];
        size_t o = (size_t)(b * S_ + i0 + w * 16 + kg * 4 + r) * (H_ * D_) + h * D_ + fr;
#pragma unroll
        for (int cf = 0; cf < 16; ++cf)
            out[o + cf * 16] = acc[cf][r] * invl;
    }
}

// ---------------- launcher ----------------
// ws layout (byte offsets), footprint 117,440,512 B:
//   q      [0,          33554432)  fp32 [4096][2048]; later ao_h/ao_l bf16 planes
//   kvb    [33554432,   41943040)  fp32 [4096][512] (K|V)
//   k_h    [41943040,   44040192)  bf16 [2][2048][256] rope'd
//   k_l    [44040192,   46137344)
//   hs_h/l [46137344,   79691776)  later reused as ao fp32
//   wq_h/l [79691776,   96468992)  after gemm-q dead -> vT_h/vT_l (2MB each)
//   wkv_h/l[96468992,  100663296)
//   wo_h/l [100663296, 117440512)
extern "C" void kernel_launch(void* const* d_in, const int* in_sizes, int n_in,
                              void* d_out, int out_size, void* d_ws, size_t ws_size,
                              hipStream_t stream) {
    const float* hs   = (const float*)d_in[0];
    const float* mask = (const float*)d_in[1];
    const int*   pos  = (const int*)d_in[2];
    const float* wq   = (const float*)d_in[3];
    const float* wk   = (const float*)d_in[4];
    const float* wv   = (const float*)d_in[5];
    const float* wo   = (const float*)d_in[6];
    float* out = (float*)d_out;

    char* ws = (char*)d_ws;
    float*          q     = (float*)(ws + 0);
    float*          kvb   = (float*)(ws + 33554432);
    unsigned short* k_h   = (unsigned short*)(ws + 41943040);
    unsigned short* k_l   = (unsigned short*)(ws + 44040192);
    unsigned short* hs_h  = (unsigned short*)(ws + 46137344);
    unsigned short* hs_l  = (unsigned short*)(ws + 62914560);
    float*          ao    = (float*)(ws + 46137344);   // overlays hs planes (dead)
    unsigned short* wq_h  = (unsigned short*)(ws + 79691776);
    unsigned short* wq_l  = (unsigned short*)(ws + 88080384);
    unsigned short* vT_h  = (unsigned short*)(ws + 79691776);  // overlays wq_h (dead after gemm-q)
    unsigned short* vT_l  = (unsigned short*)(ws + 81788928);
    unsigned short* wkv_h = (unsigned short*)(ws + 96468992);
    unsigned short* wkv_l = (unsigned short*)(ws + 98566144);
    unsigned short* wo_h  = (unsigned short*)(ws + 100663296);
    unsigned short* wo_l  = (unsigned short*)(ws + 109051904);
    unsigned short* ao_h  = (unsigned short*)(ws + 0);         // overlays q (dead by then)
    unsigned short* ao_l  = (unsigned short*)(ws + 16777216);

    const int M = B_ * S_;  // 4096

    // 1) splits
    split_bf16<<<dim3(2097152 / 256), dim3(256), 0, stream>>>(hs, hs_h, hs_l, 2097152);
    split_bf16<<<dim3(1048576 / 256), dim3(256), 0, stream>>>(wq, wq_h, wq_l, 1048576);
    split_bf16<<<dim3(131072 / 256),  dim3(256), 0, stream>>>(wk, wkv_h, wkv_l, 131072);
    split_bf16<<<dim3(131072 / 256),  dim3(256), 0, stream>>>(wv, wkv_h + 524288, wkv_l + 524288, 131072);
    split_bf16<<<dim3(1048576 / 256), dim3(256), 0, stream>>>(wo, wo_h, wo_l, 1048576);

    // 2) projections
    gemm_mfma_split<<<dim3(M / 128, 16), dim3(256), 0, stream>>>(hs_h, hs_l, wq_h, wq_l, q,   M, H_ * D_, HID_);
    gemm_mfma_split<<<dim3(M / 128, 4),  dim3(256), 0, stream>>>(hs_h, hs_l, wkv_h, wkv_l, kvb, M, KV_STRIDE, HID_);

    // 3) RoPE (q in place; K -> bf16 planes)   4) V transpose+split (vT overlays dead wq)
    rope_kernel<<<dim3(B_ * S_), dim3(128), 0, stream>>>(q, kvb, k_h, k_l, pos);
    vsplitT<<<dim3(256), dim3(256), 0, stream>>>(kvb, vT_h, vT_l);

    // 5) attention (MFMA)
    attn_mfma<<<dim3(B_ * H_ * (S_ / 128)), dim3(512), 0, stream>>>(q, k_h, k_l, vT_h, vT_l, mask, ao);

    // 6) output projection
    split_bf16<<<dim3(2097152 / 256), dim3(256), 0, stream>>>(ao, ao_h, ao_l, 2097152);
    gemm_mfma_split<<<dim3(M / 128, 16), dim3(256), 0, stream>>>(ao_h, ao_l, wo_h, wo_l, out, M, HID_, HID_);
}

// Round 7
// 722.647 us; speedup vs baseline: 2.5274x; 1.1400x over previous
//
#include <hip/hip_runtime.h>
#include <math.h>

// Problem constants
#define B_ 2
#define S_ 2048
#define HID_ 2048
#define H_ 8
#define D_ 256
#define KV_STRIDE 512   // kv_cat: [4096][512] = K(0..255) | V(256..511)

typedef __attribute__((ext_vector_type(8))) __bf16 bf16x8;
typedef __attribute__((ext_vector_type(8))) unsigned short u16x8;
typedef __attribute__((ext_vector_type(4))) float f32x4;

__device__ __forceinline__ unsigned short bf16_rne(float x) {
    unsigned int u = __float_as_uint(x);
    return (unsigned short)((u + 0x7FFFu + ((u >> 16) & 1u)) >> 16);
}

// ---------------- fp32 -> bf16 hi/lo split (x ~= hi + lo, err ~2^-17 |x|) ----------------
__global__ __launch_bounds__(256) void split_bf16(const float* __restrict__ x,
                                                  unsigned short* __restrict__ h,
                                                  unsigned short* __restrict__ l,
                                                  int n4) {
    int i = blockIdx.x * 256 + threadIdx.x;
    if (i >= n4) return;
    float4 v = ((const float4*)x)[i];
    ushort4 hh, ll;
    hh.x = bf16_rne(v.x); ll.x = bf16_rne(v.x - __uint_as_float((unsigned int)hh.x << 16));
    hh.y = bf16_rne(v.y); ll.y = bf16_rne(v.y - __uint_as_float((unsigned int)hh.y << 16));
    hh.z = bf16_rne(v.z); ll.z = bf16_rne(v.z - __uint_as_float((unsigned int)hh.z << 16));
    hh.w = bf16_rne(v.w); ll.w = bf16_rne(v.w - __uint_as_float((unsigned int)hh.w << 16));
    ((ushort4*)h)[i] = hh;
    ((ushort4*)l)[i] = ll;
}

// ---------------- split-bf16 MFMA GEMM: C[M,N] = A[M,K] @ W[N,K]^T (VALIDATED R3) --------
__global__ __launch_bounds__(256) void gemm_mfma_split(
    const unsigned short* __restrict__ Ah, const unsigned short* __restrict__ Al,
    const unsigned short* __restrict__ Wh, const unsigned short* __restrict__ Wl,
    float* __restrict__ C, int M, int N, int K)
{
    __shared__ unsigned short As[2][128][40];
    __shared__ unsigned short Bs[2][128][40];

    const int tid  = threadIdx.x;
    const int lane = tid & 63;
    const int w    = tid >> 6;
    const int wr   = w >> 1, wc = w & 1;
    const int fr   = lane & 15;
    const int ko   = (lane >> 4) * 8;
    const int bm   = blockIdx.x * 128, bn = blockIdx.y * 128;

    const int srow = tid >> 1;
    const int skc  = (tid & 1) * 16;
    const unsigned short* gAh = Ah + (size_t)(bm + srow) * K + skc;
    const unsigned short* gAl = Al + (size_t)(bm + srow) * K + skc;
    const unsigned short* gWh = Wh + (size_t)(bn + srow) * K + skc;
    const unsigned short* gWl = Wl + (size_t)(bn + srow) * K + skc;

    f32x4 acc[4][4];
#pragma unroll
    for (int i = 0; i < 4; ++i)
#pragma unroll
        for (int j = 0; j < 4; ++j)
#pragma unroll
            for (int r = 0; r < 4; ++r) acc[i][j][r] = 0.f;

    u16x8 ra0 = ((const u16x8*)gAh)[0], ra1 = ((const u16x8*)gAh)[1];
    u16x8 ra2 = ((const u16x8*)gAl)[0], ra3 = ((const u16x8*)gAl)[1];
    u16x8 rb0 = ((const u16x8*)gWh)[0], rb1 = ((const u16x8*)gWh)[1];
    u16x8 rb2 = ((const u16x8*)gWl)[0], rb3 = ((const u16x8*)gWl)[1];

    for (int k0 = 0; k0 < K; k0 += 32) {
        *(u16x8*)&As[0][srow][skc]     = ra0;
        *(u16x8*)&As[0][srow][skc + 8] = ra1;
        *(u16x8*)&As[1][srow][skc]     = ra2;
        *(u16x8*)&As[1][srow][skc + 8] = ra3;
        *(u16x8*)&Bs[0][srow][skc]     = rb0;
        *(u16x8*)&Bs[0][srow][skc + 8] = rb1;
        *(u16x8*)&Bs[1][srow][skc]     = rb2;
        *(u16x8*)&Bs[1][srow][skc + 8] = rb3;
        __syncthreads();

        if (k0 + 32 < K) {
            const unsigned short* nAh = gAh + k0 + 32;
            const unsigned short* nAl = gAl + k0 + 32;
            const unsigned short* nWh = gWh + k0 + 32;
            const unsigned short* nWl = gWl + k0 + 32;
            ra0 = ((const u16x8*)nAh)[0]; ra1 = ((const u16x8*)nAh)[1];
            ra2 = ((const u16x8*)nAl)[0]; ra3 = ((const u16x8*)nAl)[1];
            rb0 = ((const u16x8*)nWh)[0]; rb1 = ((const u16x8*)nWh)[1];
            rb2 = ((const u16x8*)nWl)[0]; rb3 = ((const u16x8*)nWl)[1];
        }

        bf16x8 ah[4], al4[4], bh[4], bl[4];
#pragma unroll
        for (int i = 0; i < 4; ++i) {
            ah[i]  = *(const bf16x8*)&As[0][wr * 64 + i * 16 + fr][ko];
            al4[i] = *(const bf16x8*)&As[1][wr * 64 + i * 16 + fr][ko];
            bh[i]  = *(const bf16x8*)&Bs[0][wc * 64 + i * 16 + fr][ko];
            bl[i]  = *(const bf16x8*)&Bs[1][wc * 64 + i * 16 + fr][ko];
        }
#pragma unroll
        for (int i = 0; i < 4; ++i)
#pragma unroll
            for (int j = 0; j < 4; ++j) {
                acc[i][j] = __builtin_amdgcn_mfma_f32_16x16x32_bf16(ah[i],  bh[j], acc[i][j], 0, 0, 0);
                acc[i][j] = __builtin_amdgcn_mfma_f32_16x16x32_bf16(ah[i],  bl[j], acc[i][j], 0, 0, 0);
                acc[i][j] = __builtin_amdgcn_mfma_f32_16x16x32_bf16(al4[i], bh[j], acc[i][j], 0, 0, 0);
            }
        __syncthreads();
    }

#pragma unroll
    for (int i = 0; i < 4; ++i) {
        int r0 = bm + wr * 64 + i * 16 + (lane >> 4) * 4;
#pragma unroll
        for (int j = 0; j < 4; ++j) {
            int c = bn + wc * 64 + j * 16 + fr;
#pragma unroll
            for (int r = 0; r < 4; ++r)
                C[(size_t)(r0 + r) * N + c] = acc[i][j][r];
        }
    }
}

// ---------------- RoPE: q in place (fp32); K -> rope'd bf16 hi/lo planes [B][S][256] -----
__global__ __launch_bounds__(128) void rope_kernel(float* __restrict__ q,
                                                   const float* __restrict__ kv,
                                                   unsigned short* __restrict__ k_h,
                                                   unsigned short* __restrict__ k_l,
                                                   const int* __restrict__ pos) {
    int bs = blockIdx.x;
    int d = threadIdx.x;            // 0..127 (pair index)
    float p = (float)pos[bs];
    float inv = expf(-(2.0f * (float)d / (float)D_) * 9.210340371976184f);  // log(10000)
    float sn, cs;
    sincosf(p * inv, &sn, &cs);

    float* qp = q + (size_t)bs * (H_ * D_);
#pragma unroll
    for (int h = 0; h < H_; ++h) {
        float x1 = qp[h * D_ + d];
        float x2 = qp[h * D_ + d + 128];
        qp[h * D_ + d]       = x1 * cs - x2 * sn;
        qp[h * D_ + d + 128] = x2 * cs + x1 * sn;
    }
    const float* kp = kv + (size_t)bs * KV_STRIDE;
    float x1 = kp[d], x2 = kp[d + 128];
    float y1 = x1 * cs - x2 * sn;
    float y2 = x2 * cs + x1 * sn;
    unsigned short h1 = bf16_rne(y1);
    unsigned short h2 = bf16_rne(y2);
    size_t o = (size_t)bs * D_ + d;
    k_h[o]       = h1;
    k_l[o]       = bf16_rne(y1 - __uint_as_float((unsigned int)h1 << 16));
    k_h[o + 128] = h2;
    k_l[o + 128] = bf16_rne(y2 - __uint_as_float((unsigned int)h2 << 16));
}

// ---------------- V: transpose + split -> vT_h/vT_l [B][256][S] bf16 ----------------
__global__ __launch_bounds__(256) void vsplitT(const float* __restrict__ kvb,
                                               unsigned short* __restrict__ vTh,
                                               unsigned short* __restrict__ vTl) {
    __shared__ float ts[64][65];
    const int blk = blockIdx.x;       // b*128 + dt*32 + jt
    const int b  = blk >> 7;
    const int dt = (blk >> 5) & 3;
    const int jt = blk & 31;
    const int tid = threadIdx.x;
    const int jj = tid >> 2;            // 0..63
    const int dc = (tid & 3) * 16;
    const float* src = kvb + (size_t)(b * S_ + jt * 64 + jj) * KV_STRIDE + 256 + dt * 64 + dc;
#pragma unroll
    for (int i = 0; i < 16; i += 4) {
        float4 v4 = *(const float4*)(src + i);
        ts[jj][dc + i + 0] = v4.x;
        ts[jj][dc + i + 1] = v4.y;
        ts[jj][dc + i + 2] = v4.z;
        ts[jj][dc + i + 3] = v4.w;
    }
    __syncthreads();
    const int dd = tid >> 2;            // 0..63
    const int jc = (tid & 3) * 16;
    size_t o = (size_t)(b * 256 + dt * 64 + dd) * S_ + jt * 64 + jc;
#pragma unroll
    for (int i = 0; i < 16; i += 8) {
        u16x8 hh, ll;
#pragma unroll
        for (int e = 0; e < 8; ++e) {
            float f = ts[jc + i + e][dd];
            unsigned short hb = bf16_rne(f);
            hh[e] = hb;
            ll[e] = bf16_rne(f - __uint_as_float((unsigned int)hb << 16));
        }
        *(u16x8*)(vTh + o + i) = hh;
        *(u16x8*)(vTl + o + i) = ll;
    }
}

// ---------------- MFMA flash attention, j-tile=32, conflict-free chunk LDS ----------------
// Block = 512 thr = 8 waves; per block one (b,h) x 128 q-rows; wave w owns rows w*16..+15.
// LDS chunk layouts: element (row, k=c*8+e) stored at [c][row][e] -> every 64-lane
// ds_read_b128 distributes 8 words/bank (hardware minimum cycles, zero excess conflicts).
// j=32: PV k=32 MFMAs fully dense (no pads anywhere -> no NaN hazards).
// V staged in two d-halves (16KB buffer reused) to fit LDS = 32+16+16 = 64KB exactly.
// Frag layouts (HW-validated R3/R5): A row|B col = lane&15, k=(lane>>4)*8+e; C: col=lane&15, row=(lane>>4)*4+r.
__global__ __launch_bounds__(512) void attn_mfma(
    const float* __restrict__ q,
    const unsigned short* __restrict__ k_h,
    const unsigned short* __restrict__ k_l,
    const unsigned short* __restrict__ vTh,
    const unsigned short* __restrict__ vTl,
    const float* __restrict__ mask,
    unsigned short* __restrict__ aoh,
    unsigned short* __restrict__ aol)
{
    __shared__ __align__(16) unsigned short Ks[2][32][32][8];   // [pl][dchunk][j][e]   32768 B
    __shared__ __align__(16) unsigned short Vs[2][4][128][8];   // [pl][jchunk][d][e]   16384 B
    __shared__ __align__(16) unsigned short Ps[2][8][4][16][8]; // [pl][w][jchunk][q][e] 16384 B

    const int tid  = threadIdx.x;
    const int lane = tid & 63;
    const int w    = tid >> 6;          // 0..7
    const int fr   = lane & 15;
    const int kg   = lane >> 4;         // 0..3
    const int nqt  = S_ / 128;          // 16
    const int b    = blockIdx.x / (H_ * nqt);
    const int rem  = blockIdx.x % (H_ * nqt);
    const int h    = rem / nqt;
    const int i0   = (rem % nqt) * 128;

    // ---- Q fragments (hi/lo), rows w*16+fr, 8 d-ksteps (identical to validated R5) ----
    bf16x8 qh[8], ql[8];
    {
        const int qrow = i0 + w * 16 + fr;
        const float* qp = q + (size_t)(b * S_ + qrow) * (H_ * D_) + h * D_ + kg * 8;
#pragma unroll
        for (int ks = 0; ks < 8; ++ks) {
            float4 f0 = *(const float4*)(qp + ks * 32);
            float4 f1 = *(const float4*)(qp + ks * 32 + 4);
            float f[8] = {f0.x, f0.y, f0.z, f0.w, f1.x, f1.y, f1.z, f1.w};
            u16x8 hh, ll;
#pragma unroll
            for (int e = 0; e < 8; ++e) {
                unsigned short hb = bf16_rne(f[e]);
                hh[e] = hb;
                ll[e] = bf16_rne(f[e] - __uint_as_float((unsigned int)hb << 16));
            }
            qh[ks] = *(bf16x8*)&hh;
            ql[ks] = *(bf16x8*)&ll;
        }
    }

    f32x4 acc[16];
#pragma unroll
    for (int cf = 0; cf < 16; ++cf) acc[cf] = f32x4{0.f, 0.f, 0.f, 0.f};
    float m_run[4], l_run[4];
#pragma unroll
    for (int r = 0; r < 4; ++r) { m_run[r] = -1e30f; l_run[r] = 0.f; }

    // ---- staging maps (512 threads; sp = hi/lo plane) ----
    const int sp  = tid >> 8;
    const int t8  = tid & 255;
    const int sj  = t8 >> 3;             // K: j row 0..31
    const int sdc = (t8 & 7) * 4;        // K: dchunk base {0,4,..,28}
    const int svd = t8 >> 1;             // V: d-local 0..127
    const int sjc = (t8 & 1) * 2;        // V: jchunk base {0,2}
    const unsigned short* gK  = (sp ? k_l : k_h) + (size_t)(b * S_ + sj) * 256 + sdc * 8;
    const unsigned short* gVA = (sp ? vTl : vTh) + (size_t)(b * 256 + svd) * S_ + sjc * 8;
    const unsigned short* gVB = gVA + (size_t)128 * S_;

    u16x8 rk[4], rva[2], rvb[2];
#pragma unroll
    for (int i = 0; i < 4; ++i) rk[i] = *(const u16x8*)(gK + i * 8);
#pragma unroll
    for (int i = 0; i < 2; ++i) { rva[i] = *(const u16x8*)(gVA + i * 8);
                                  rvb[i] = *(const u16x8*)(gVB + i * 8); }

    const float scale = 0.0625f;  // 1/sqrt(256)

    for (int j0 = 0; j0 < S_; j0 += 32) {
        __syncthreads();   // prev tile's reads done; K/V-A writable
#pragma unroll
        for (int i = 0; i < 4; ++i) *(u16x8*)&Ks[sp][sdc + i][sj][0] = rk[i];
#pragma unroll
        for (int i = 0; i < 2; ++i) *(u16x8*)&Vs[sp][sjc + i][svd][0] = rva[i];
        __syncthreads();   // staged
        if (j0 + 32 < S_) {   // prefetch next K + V-A (hides under QK/PV-A)
#pragma unroll
            for (int i = 0; i < 4; ++i) rk[i]  = *(const u16x8*)(gK  + (size_t)(j0 + 32) * 256 + i * 8);
#pragma unroll
            for (int i = 0; i < 2; ++i) rva[i] = *(const u16x8*)(gVA + (j0 + 32) + i * 8);
        }

        // ---- QK^T (3-term split), two j-frags ----
        f32x4 sc0 = {0.f, 0.f, 0.f, 0.f}, sc1 = {0.f, 0.f, 0.f, 0.f};
#pragma unroll
        for (int ks = 0; ks < 8; ++ks) {
            const int dc = ks * 4 + kg;
            bf16x8 bh0 = *(const bf16x8*)&Ks[0][dc][fr][0];
            bf16x8 bl0 = *(const bf16x8*)&Ks[1][dc][fr][0];
            bf16x8 bh1 = *(const bf16x8*)&Ks[0][dc][16 + fr][0];
            bf16x8 bl1 = *(const bf16x8*)&Ks[1][dc][16 + fr][0];
            sc0 = __builtin_amdgcn_mfma_f32_16x16x32_bf16(qh[ks], bh0, sc0, 0, 0, 0);
            sc0 = __builtin_amdgcn_mfma_f32_16x16x32_bf16(qh[ks], bl0, sc0, 0, 0, 0);
            sc0 = __builtin_amdgcn_mfma_f32_16x16x32_bf16(ql[ks], bh0, sc0, 0, 0, 0);
            sc1 = __builtin_amdgcn_mfma_f32_16x16x32_bf16(qh[ks], bh1, sc1, 0, 0, 0);
            sc1 = __builtin_amdgcn_mfma_f32_16x16x32_bf16(qh[ks], bl1, sc1, 0, 0, 0);
            sc1 = __builtin_amdgcn_mfma_f32_16x16x32_bf16(ql[ks], bh1, sc1, 0, 0, 0);
        }

        // ---- scale + mask; C elem r: row q = kg*4+r, col j = jf*16+fr ----
        float sv0[4], sv1[4];
        const float* mrow = &mask[(size_t)(b * S_ + i0 + w * 16 + kg * 4) * S_ + j0 + fr];
#pragma unroll
        for (int r = 0; r < 4; ++r) {
            sv0[r] = sc0[r] * scale + mrow[(size_t)r * S_];
            sv1[r] = sc1[r] * scale + mrow[(size_t)r * S_ + 16];
        }

        // ---- row max over 32 j (shfl within 16-lane group) ----
        float rmax[4];
#pragma unroll
        for (int r = 0; r < 4; ++r) rmax[r] = fmaxf(sv0[r], sv1[r]);
#pragma unroll
        for (int off = 1; off < 16; off <<= 1)
#pragma unroll
            for (int r = 0; r < 4; ++r)
                rmax[r] = fmaxf(rmax[r], __shfl_xor(rmax[r], off));

        // ---- online softmax; P hi/lo into own wave's chunk region ----
        float corr[4], psum[4];
#pragma unroll
        for (int r = 0; r < 4; ++r) {
            float mn = fmaxf(m_run[r], rmax[r]);
            corr[r] = __expf(m_run[r] - mn);
            m_run[r] = mn;
            float p0 = __expf(sv0[r] - mn);
            float p1 = __expf(sv1[r] - mn);
            psum[r] = p0 + p1;
            unsigned short p0h = bf16_rne(p0);
            unsigned short p1h = bf16_rne(p1);
            Ps[0][w][(fr >> 3)][kg * 4 + r][fr & 7]     = p0h;
            Ps[1][w][(fr >> 3)][kg * 4 + r][fr & 7]     = bf16_rne(p0 - __uint_as_float((unsigned int)p0h << 16));
            Ps[0][w][2 + (fr >> 3)][kg * 4 + r][fr & 7] = p1h;
            Ps[1][w][2 + (fr >> 3)][kg * 4 + r][fr & 7] = bf16_rne(p1 - __uint_as_float((unsigned int)p1h << 16));
        }
#pragma unroll
        for (int off = 1; off < 16; off <<= 1)
#pragma unroll
            for (int r = 0; r < 4; ++r) psum[r] += __shfl_xor(psum[r], off);
#pragma unroll
        for (int r = 0; r < 4; ++r) l_run[r] = l_run[r] * corr[r] + psum[r];

        // ---- P frags (own wave; same-wave LDS RAW ordered by lgkmcnt) ----
        bf16x8 pah = *(const bf16x8*)&Ps[0][w][kg][fr][0];
        bf16x8 pal = *(const bf16x8*)&Ps[1][w][kg][fr][0];

        // ---- rescale O ----
#pragma unroll
        for (int cf = 0; cf < 16; ++cf)
#pragma unroll
            for (int r = 0; r < 4; ++r) acc[cf][r] *= corr[r];

        // ---- PV half A: d 0..127 (cf 0..7), k=32 dense ----
#pragma unroll
        for (int cf = 0; cf < 8; ++cf) {
            bf16x8 vh = *(const bf16x8*)&Vs[0][kg][cf * 16 + fr][0];
            bf16x8 vl = *(const bf16x8*)&Vs[1][kg][cf * 16 + fr][0];
            acc[cf] = __builtin_amdgcn_mfma_f32_16x16x32_bf16(pah, vh, acc[cf], 0, 0, 0);
            acc[cf] = __builtin_amdgcn_mfma_f32_16x16x32_bf16(pah, vl, acc[cf], 0, 0, 0);
            acc[cf] = __builtin_amdgcn_mfma_f32_16x16x32_bf16(pal, vh, acc[cf], 0, 0, 0);
        }

        __syncthreads();   // all waves done with V half A
#pragma unroll
        for (int i = 0; i < 2; ++i) *(u16x8*)&Vs[sp][sjc + i][svd][0] = rvb[i];
        __syncthreads();   // half B staged
        if (j0 + 32 < S_)
#pragma unroll
            for (int i = 0; i < 2; ++i) rvb[i] = *(const u16x8*)(gVB + (j0 + 32) + i * 8);

        // ---- PV half B: d 128..255 (cf 8..15) ----
#pragma unroll
        for (int cf = 8; cf < 16; ++cf) {
            bf16x8 vh = *(const bf16x8*)&Vs[0][kg][(cf - 8) * 16 + fr][0];
            bf16x8 vl = *(const bf16x8*)&Vs[1][kg][(cf - 8) * 16 + fr][0];
            acc[cf] = __builtin_amdgcn_mfma_f32_16x16x32_bf16(pah, vh, acc[cf], 0, 0, 0);
            acc[cf] = __builtin_amdgcn_mfma_f32_16x16x32_bf16(pah, vl, acc[cf], 0, 0, 0);
            acc[cf] = __builtin_amdgcn_mfma_f32_16x16x32_bf16(pal, vh, acc[cf], 0, 0, 0);
        }
    }

    // ---- epilogue: normalize, split to bf16 hi/lo planes directly (saves ao fp32 pass) ----
#pragma unroll
    for (int r = 0; r < 4; ++r) {
        float invl = 1.0f / l_run[r];
        size_t o = (size_t)(b * S_ + i0 + w * 16 + kg * 4 + r) * (H_ * D_) + h * D_ + fr;
#pragma unroll
        for (int cf = 0; cf < 16; ++cf) {
            float v = acc[cf][r] * invl;
            unsigned short hb = bf16_rne(v);
            aoh[o + cf * 16] = hb;
            aol[o + cf * 16] = bf16_rne(v - __uint_as_float((unsigned int)hb << 16));
        }
    }
}

// ---------------- launcher ----------------
// ws layout (byte offsets), footprint 117,440,512 B:
//   q      [0,          33554432)  fp32 [4096][2048]
//   kvb    [33554432,   41943040)  fp32 [4096][512] (K|V)
//   k_h    [41943040,   44040192)  bf16 [2][2048][256] rope'd
//   k_l    [44040192,   46137344)
//   ao_h   [46137344,   62914560)  bf16 plane (overlays dead hs_h)
//   ao_l   [62914560,   79691776)  bf16 plane (overlays dead hs_l)
//   wq_h/l [79691776,   96468992)  after gemm-q dead -> vT_h/vT_l (2MB each)
//   wkv_h/l[96468992,  100663296)
//   wo_h/l [100663296, 117440512)
extern "C" void kernel_launch(void* const* d_in, const int* in_sizes, int n_in,
                              void* d_out, int out_size, void* d_ws, size_t ws_size,
                              hipStream_t stream) {
    const float* hs   = (const float*)d_in[0];
    const float* mask = (const float*)d_in[1];
    const int*   pos  = (const int*)d_in[2];
    const float* wq   = (const float*)d_in[3];
    const float* wk   = (const float*)d_in[4];
    const float* wv   = (const float*)d_in[5];
    const float* wo   = (const float*)d_in[6];
    float* out = (float*)d_out;

    char* ws = (char*)d_ws;
    float*          q     = (float*)(ws + 0);
    float*          kvb   = (float*)(ws + 33554432);
    unsigned short* k_h   = (unsigned short*)(ws + 41943040);
    unsigned short* k_l   = (unsigned short*)(ws + 44040192);
    unsigned short* hs_h  = (unsigned short*)(ws + 46137344);
    unsigned short* hs_l  = (unsigned short*)(ws + 62914560);
    unsigned short* ao_h  = (unsigned short*)(ws + 46137344);  // overlays hs_h (dead after gemms)
    unsigned short* ao_l  = (unsigned short*)(ws + 62914560);  // overlays hs_l (dead after gemms)
    unsigned short* wq_h  = (unsigned short*)(ws + 79691776);
    unsigned short* wq_l  = (unsigned short*)(ws + 88080384);
    unsigned short* vT_h  = (unsigned short*)(ws + 79691776);  // overlays wq_h (dead after gemm-q)
    unsigned short* vT_l  = (unsigned short*)(ws + 81788928);
    unsigned short* wkv_h = (unsigned short*)(ws + 96468992);
    unsigned short* wkv_l = (unsigned short*)(ws + 98566144);
    unsigned short* wo_h  = (unsigned short*)(ws + 100663296);
    unsigned short* wo_l  = (unsigned short*)(ws + 109051904);

    const int M = B_ * S_;  // 4096

    // 1) splits
    split_bf16<<<dim3(2097152 / 256), dim3(256), 0, stream>>>(hs, hs_h, hs_l, 2097152);
    split_bf16<<<dim3(1048576 / 256), dim3(256), 0, stream>>>(wq, wq_h, wq_l, 1048576);
    split_bf16<<<dim3(131072 / 256),  dim3(256), 0, stream>>>(wk, wkv_h, wkv_l, 131072);
    split_bf16<<<dim3(131072 / 256),  dim3(256), 0, stream>>>(wv, wkv_h + 524288, wkv_l + 524288, 131072);
    split_bf16<<<dim3(1048576 / 256), dim3(256), 0, stream>>>(wo, wo_h, wo_l, 1048576);

    // 2) projections
    gemm_mfma_split<<<dim3(M / 128, 16), dim3(256), 0, stream>>>(hs_h, hs_l, wq_h, wq_l, q,   M, H_ * D_, HID_);
    gemm_mfma_split<<<dim3(M / 128, 4),  dim3(256), 0, stream>>>(hs_h, hs_l, wkv_h, wkv_l, kvb, M, KV_STRIDE, HID_);

    // 3) RoPE (q in place; K -> bf16 planes)   4) V transpose+split (vT overlays dead wq)
    rope_kernel<<<dim3(B_ * S_), dim3(128), 0, stream>>>(q, kvb, k_h, k_l, pos);
    vsplitT<<<dim3(256), dim3(256), 0, stream>>>(kvb, vT_h, vT_l);

    // 5) attention (MFMA, writes ao bf16 planes directly)
    attn_mfma<<<dim3(B_ * H_ * (S_ / 128)), dim3(512), 0, stream>>>(q, k_h, k_l, vT_h, vT_l, mask, ao_h, ao_l);

    // 6) output projection
    gemm_mfma_split<<<dim3(M / 128, 16), dim3(256), 0, stream>>>(ao_h, ao_l, wo_h, wo_l, out, M, HID_, HID_);
}